// Round 2
// baseline (769.347 us; speedup 1.0000x reference)
//
#include <hip/hip_runtime.h>
#include <hip/hip_bf16.h>

#define NR 4096
#define DD 512
#define BM 128
#define BN 128
#define BK 64
#define LDK 72   // BK + 8 pad
#define CAP 64   // max nnz per adjacency row (mean 20.5, P(>64) ~ 1e-22)

typedef __bf16 bf16x8 __attribute__((ext_vector_type(8)));
typedef float f32x4 __attribute__((ext_vector_type(4)));
typedef unsigned short u16;

__device__ __forceinline__ u16 f2bf(float x) {
    __hip_bfloat16 h = __float2bfloat16(x);
    return *reinterpret_cast<u16*>(&h);
}

// ---------------------------------------------------------------------------
// Kernel 1: row-normalize z1,z2 -> bf16, and d12[i] = zn1[i]·zn2[i] (fp32)
// ---------------------------------------------------------------------------
__global__ void norm_kernel(const float* z1, const float* z2,
                            u16* zn1, u16* zn2, float* d12) {
    const int row = blockIdx.x;
    const int t = threadIdx.x;           // 256 threads
    const float* r1 = z1 + (size_t)row * DD;
    const float* r2 = z2 + (size_t)row * DD;
    float a0 = r1[t], a1 = r1[t + 256];
    float b0 = r2[t], b1 = r2[t + 256];
    float ss1 = a0 * a0 + a1 * a1;
    float ss2 = b0 * b0 + b1 * b1;
    #pragma unroll
    for (int m = 1; m < 64; m <<= 1) {
        ss1 += __shfl_xor(ss1, m);
        ss2 += __shfl_xor(ss2, m);
    }
    __shared__ float s1s[4], s2s[4], ds[4];
    const int wid = t >> 6, lane = t & 63;
    if (lane == 0) { s1s[wid] = ss1; s2s[wid] = ss2; }
    __syncthreads();
    const float n1 = s1s[0] + s1s[1] + s1s[2] + s1s[3];
    const float n2 = s2s[0] + s2s[1] + s2s[2] + s2s[3];
    const float inv1 = 1.0f / fmaxf(sqrtf(n1), 1e-12f);
    const float inv2 = 1.0f / fmaxf(sqrtf(n2), 1e-12f);
    const float u0 = a0 * inv1, u1 = a1 * inv1;
    const float v0 = b0 * inv2, v1 = b1 * inv2;
    zn1[(size_t)row * DD + t]       = f2bf(u0);
    zn1[(size_t)row * DD + t + 256] = f2bf(u1);
    zn2[(size_t)row * DD + t]       = f2bf(v0);
    zn2[(size_t)row * DD + t + 256] = f2bf(v1);
    float dp = u0 * v0 + u1 * v1;
    #pragma unroll
    for (int m = 1; m < 64; m <<= 1) dp += __shfl_xor(dp, m);
    if (lane == 0) ds[wid] = dp;
    __syncthreads();
    if (t == 0) d12[row] = ds[0] + ds[1] + ds[2] + ds[3];
}

// ---------------------------------------------------------------------------
// Kernel 2: sparsify the 6 binary adjacency matrices.
// One block per (row, matrix). Coalesced float4 streaming; nonzero columns
// compacted into idx[(m*NR+row)*CAP + k]; count into cnts and asum (float).
// ---------------------------------------------------------------------------
__global__ __launch_bounds__(256)
void sparsify_kernel(const float* m0, const float* m1, const float* m2,
                     const float* m3, const float* m4, const float* m5,
                     int* cnts, int* idx, float* asum) {
    const int row = blockIdx.x;
    const int m = blockIdx.y;
    const int t = threadIdx.x;
    const float* M = (m == 0) ? m0 : (m == 1) ? m1 : (m == 2) ? m2
                   : (m == 3) ? m3 : (m == 4) ? m4 : m5;
    const float* rowp = M + (size_t)row * NR;
    __shared__ int s_cnt;
    __shared__ int s_idx[CAP];
    if (t == 0) s_cnt = 0;
    __syncthreads();
    #pragma unroll
    for (int q = 0; q < 4; q++) {
        const int vi = t + 256 * q;
        const float4 v = ((const float4*)rowp)[vi];
        const int col = vi * 4;
        if (v.x != 0.f) { int p = atomicAdd(&s_cnt, 1); if (p < CAP) s_idx[p] = col; }
        if (v.y != 0.f) { int p = atomicAdd(&s_cnt, 1); if (p < CAP) s_idx[p] = col + 1; }
        if (v.z != 0.f) { int p = atomicAdd(&s_cnt, 1); if (p < CAP) s_idx[p] = col + 2; }
        if (v.w != 0.f) { int p = atomicAdd(&s_cnt, 1); if (p < CAP) s_idx[p] = col + 3; }
    }
    __syncthreads();
    const int c = min(s_cnt, CAP);
    const size_t base = (size_t)m * NR + row;
    if (t < c) idx[base * CAP + t] = s_idx[t];
    if (t == 0) { cnts[base] = c; asum[base] = (float)s_cnt; }
}

// ---------------------------------------------------------------------------
// Kernel 3: fused dual-GEMM + exp row sums (NO adjacency work).
// blockIdx.z==0: A=zn1[I], B1=zn1[J] (S11 -> pass0), B2=zn2[J] (S12 -> pass1)
// blockIdx.z==1: A=zn2[I], B1=zn2[J] (S22 -> pass2), B2=zn1[J] (S21 -> pass3)
// rs[pass][tau][i] += sum_j exp(S[i,j]/tau), tau in {0.8, 0.64, 0.72}
// ---------------------------------------------------------------------------
__global__ __launch_bounds__(256, 2)
void score_kernel(const u16* zn1, const u16* zn2, float* rs) {
    const int z = blockIdx.z;
    const int Ib = blockIdx.y * BM;
    const int Jb = blockIdx.x * BN;
    const u16* Ag  = z ? zn2 : zn1;
    const u16* B1g = z ? zn2 : zn1;
    const u16* B2g = z ? zn1 : zn2;

    __shared__ u16 As[BM][LDK];
    __shared__ u16 Bs1[BN][LDK];
    __shared__ u16 Bs2[BN][LDK];

    const int tid = threadIdx.x;
    const int lane = tid & 63;
    const int wid = tid >> 6;
    const int wm = wid >> 1, wn = wid & 1;   // 2x2 waves, 64x64 each
    const int quad = lane >> 4, lcol = lane & 15;

    f32x4 acc1[4][4], acc2[4][4];
    #pragma unroll
    for (int a = 0; a < 4; a++)
        #pragma unroll
        for (int b = 0; b < 4; b++) {
            acc1[a][b] = (f32x4){0.f, 0.f, 0.f, 0.f};
            acc2[a][b] = (f32x4){0.f, 0.f, 0.f, 0.f};
        }

    const int srow = tid >> 1;      // 0..127
    const int shalf = tid & 1;      // 0,1 : 32 bf16 each
    const size_t gA0 = (size_t)(Ib + srow) * DD + shalf * 32;
    const size_t gB0 = (size_t)(Jb + srow) * DD + shalf * 32;

    for (int k0 = 0; k0 < DD; k0 += BK) {
        const u16* pa  = Ag  + gA0 + k0;
        const u16* pb1 = B1g + gB0 + k0;
        const u16* pb2 = B2g + gB0 + k0;
        uint4 va[4], vb1[4], vb2[4];
        #pragma unroll
        for (int q = 0; q < 4; q++) {
            va[q]  = ((const uint4*)pa)[q];
            vb1[q] = ((const uint4*)pb1)[q];
            vb2[q] = ((const uint4*)pb2)[q];
        }
        __syncthreads();
        #pragma unroll
        for (int q = 0; q < 4; q++) {
            ((uint4*)&As[srow][shalf * 32])[q]  = va[q];
            ((uint4*)&Bs1[srow][shalf * 32])[q] = vb1[q];
            ((uint4*)&Bs2[srow][shalf * 32])[q] = vb2[q];
        }
        __syncthreads();
        #pragma unroll
        for (int kk = 0; kk < BK; kk += 32) {
            bf16x8 a[4], b1[4], b2[4];
            #pragma unroll
            for (int i = 0; i < 4; i++) {
                a[i]  = *(const bf16x8*)&As[wm * 64 + i * 16 + lcol][kk + quad * 8];
                b1[i] = *(const bf16x8*)&Bs1[wn * 64 + i * 16 + lcol][kk + quad * 8];
                b2[i] = *(const bf16x8*)&Bs2[wn * 64 + i * 16 + lcol][kk + quad * 8];
            }
            #pragma unroll
            for (int mi = 0; mi < 4; mi++)
                #pragma unroll
                for (int ni = 0; ni < 4; ni++) {
                    acc1[mi][ni] = __builtin_amdgcn_mfma_f32_16x16x32_bf16(a[mi], b1[ni], acc1[mi][ni], 0, 0, 0);
                    acc2[mi][ni] = __builtin_amdgcn_mfma_f32_16x16x32_bf16(a[mi], b2[ni], acc2[mi][ni], 0, 0, 0);
                }
        }
    }

    const float C0 = 1.8033688011112042f;  // log2(e)/0.80
    const float C1 = 2.2542110013890054f;  // log2(e)/0.64
    const float C2 = 2.0037431123457825f;  // log2(e)/0.72

    #pragma unroll
    for (int mi = 0; mi < 4; mi++) {
        #pragma unroll
        for (int reg = 0; reg < 4; reg++) {
            const int i = Ib + wm * 64 + mi * 16 + quad * 4 + reg;   // C/D: row = quad*4+reg
            float p[6] = {0.f, 0.f, 0.f, 0.f, 0.f, 0.f};
            #pragma unroll
            for (int ni = 0; ni < 4; ni++) {
                const float s1 = acc1[mi][ni][reg];
                const float s2 = acc2[mi][ni][reg];
                p[0] += __builtin_amdgcn_exp2f(s1 * C0);
                p[1] += __builtin_amdgcn_exp2f(s1 * C1);
                p[2] += __builtin_amdgcn_exp2f(s1 * C2);
                p[3] += __builtin_amdgcn_exp2f(s2 * C0);
                p[4] += __builtin_amdgcn_exp2f(s2 * C1);
                p[5] += __builtin_amdgcn_exp2f(s2 * C2);
            }
            #pragma unroll
            for (int q = 0; q < 6; q++) {
                p[q] += __shfl_xor(p[q], 1);
                p[q] += __shfl_xor(p[q], 2);
                p[q] += __shfl_xor(p[q], 4);
                p[q] += __shfl_xor(p[q], 8);
            }
            if (lcol == 0) {
                const int p1 = 2 * z, p2 = 2 * z + 1;
                atomicAdd(&rs[(p1 * 3 + 0) * NR + i], p[0]);
                atomicAdd(&rs[(p1 * 3 + 1) * NR + i], p[1]);
                atomicAdd(&rs[(p1 * 3 + 2) * NR + i], p[2]);
                atomicAdd(&rs[(p2 * 3 + 0) * NR + i], p[3]);
                atomicAdd(&rs[(p2 * 3 + 1) * NR + i], p[4]);
                atomicAdd(&rs[(p2 * 3 + 2) * NR + i], p[5]);
            }
        }
    }
}

// ---------------------------------------------------------------------------
// Kernel 4: sparse masked sums. One wave per (matrix m, row i).
// d1 = a·zn1_j, d2 = a·zn2_j where a = zn1_i (m<3) or zn2_i (m>=3).
// m<3:  intra=S11=d1 -> pass0, inter=S12=d2 -> pass1
// m>=3: intra=S22=d2 -> pass2, inter=S21=d1 -> pass3
// Each (pass, slot, i) has exactly one writer -> plain stores, no atomics.
// ---------------------------------------------------------------------------
__global__ __launch_bounds__(256)
void sparse_kernel(const u16* zn1, const u16* zn2,
                   const int* cnts, const int* idx, float* ms) {
    const int w = blockIdx.x * 4 + (threadIdx.x >> 6);
    const int lane = threadIdx.x & 63;
    const int m = w >> 12;       // 0..5
    const int i = w & (NR - 1);  // 0..4095

    const float C0 = 1.8033688011112042f;
    const float C1 = 2.2542110013890054f;
    const float C2 = 2.0037431123457825f;

    int nslot; int slot[3]; float coef[3];
    switch (m) {
        case 0: nslot = 2; slot[0] = 0; coef[0] = C0; slot[1] = 3; coef[1] = C1; break;
        case 1: nslot = 2; slot[0] = 1; coef[0] = C0; slot[1] = 4; coef[1] = C2; break;
        case 2: nslot = 1; slot[0] = 2; coef[0] = C0; break;
        case 3: nslot = 1; slot[0] = 0; coef[0] = C0; break;
        case 4: nslot = 1; slot[0] = 1; coef[0] = C0; break;
        default: nslot = 3; slot[0] = 2; coef[0] = C0; slot[1] = 3; coef[1] = C1;
                 slot[2] = 4; coef[2] = C2; break;
    }

    const u16* A = (m < 3) ? zn1 : zn2;
    float a[8];
    {
        const uint4 r = *(const uint4*)(A + (size_t)i * DD + lane * 8);
        const unsigned* u = (const unsigned*)&r;
        #pragma unroll
        for (int q = 0; q < 4; q++) {
            a[2 * q]     = __uint_as_float(u[q] << 16);
            a[2 * q + 1] = __uint_as_float(u[q] & 0xffff0000u);
        }
    }

    const size_t base = (size_t)m * NR + i;
    const int cnt = cnts[base];
    const int* ji = idx + base * CAP;

    float accv[3][2] = {{0.f, 0.f}, {0.f, 0.f}, {0.f, 0.f}};
    for (int q = 0; q < cnt; q++) {
        const int j = ji[q];
        const uint4 r1 = *(const uint4*)(zn1 + (size_t)j * DD + lane * 8);
        const uint4 r2 = *(const uint4*)(zn2 + (size_t)j * DD + lane * 8);
        const unsigned* u1 = (const unsigned*)&r1;
        const unsigned* u2 = (const unsigned*)&r2;
        float d1 = 0.f, d2 = 0.f;
        #pragma unroll
        for (int t = 0; t < 4; t++) {
            d1 += a[2 * t]     * __uint_as_float(u1[t] << 16);
            d1 += a[2 * t + 1] * __uint_as_float(u1[t] & 0xffff0000u);
            d2 += a[2 * t]     * __uint_as_float(u2[t] << 16);
            d2 += a[2 * t + 1] * __uint_as_float(u2[t] & 0xffff0000u);
        }
        #pragma unroll
        for (int msk = 1; msk < 64; msk <<= 1) {
            d1 += __shfl_xor(d1, msk);
            d2 += __shfl_xor(d2, msk);
        }
        const float e1 = (m < 3) ? d1 : d2;   // intra-pass score
        const float e2 = (m < 3) ? d2 : d1;   // inter-pass score
        for (int s = 0; s < nslot; s++) {
            accv[s][0] += __builtin_amdgcn_exp2f(e1 * coef[s]);
            accv[s][1] += __builtin_amdgcn_exp2f(e2 * coef[s]);
        }
    }
    if (lane == 0) {
        const int pb = (m < 3) ? 0 : 2;
        for (int s = 0; s < nslot; s++) {
            ms[((pb)     * 5 + slot[s]) * NR + i] = accv[s][0];
            ms[((pb + 1) * 5 + slot[s]) * NR + i] = accv[s][1];
        }
    }
}

// ---------------------------------------------------------------------------
// Kernel 5: assemble the 10 losses and the final scalar.
// ---------------------------------------------------------------------------
__global__ void finalize_kernel(const float* rs, const float* ms, const float* asum,
                                const float* d12, float* out) {
    const int t = threadIdx.x;   // 256
    const int tA[5] = {0, 0, 0, 1, 2};
    const int kA[5] = {0, 1, 2, 3, 4};
    const int aA[5] = {0, 1, 2, 0, 1};
    const int aB[5] = {3, 4, 5, 5, 5};
    const float it[3] = {1.25f, 1.5625f, 1.3888888888888888f};
    const float e1t[3] = {expf(1.25f), expf(1.5625f), expf(1.3888888888888888f)};

    float LA[5] = {0, 0, 0, 0, 0}, LB[5] = {0, 0, 0, 0, 0};
    float sc = 0.f, sm = 0.f, sf = 0.f;

    for (int i = t; i < NR; i += 256) {
        const float d = d12[i];
        float ed[3];
        ed[0] = __expf(d * it[0]); ed[1] = __expf(d * it[1]); ed[2] = __expf(d * it[2]);
        float R[4][3], M[4][5], A6[6];
        #pragma unroll
        for (int p = 0; p < 4; p++) {
            #pragma unroll
            for (int tt = 0; tt < 3; tt++) R[p][tt] = rs[(p * 3 + tt) * NR + i];
            #pragma unroll
            for (int k = 0; k < 5; k++) M[p][k] = ms[(p * 5 + k) * NR + i];
        }
        #pragma unroll
        for (int a = 0; a < 6; a++) A6[a] = asum[a * NR + i];

        #pragma unroll
        for (int c = 0; c < 5; c++) {
            const int tt = tA[c], k = kA[c];
            float pos = ed[tt] + M[0][k] + M[1][k];
            float den = R[0][tt] + R[1][tt] - e1t[tt];
            float cnt = 2.f * A6[aA[c]] + 1.f;
            LA[c] += __logf(pos / den) / cnt;
            pos = ed[tt] + M[2][k] + M[3][k];
            den = R[2][tt] + R[3][tt] - e1t[tt];
            cnt = 2.f * A6[aB[c]] + 1.f;
            LB[c] += __logf(pos / den) / cnt;
        }
        sc += A6[0]; sm += A6[1]; sf += A6[2];
    }

    __shared__ float red[256];
    float vals[13] = {LA[0], LA[1], LA[2], LA[3], LA[4],
                      LB[0], LB[1], LB[2], LB[3], LB[4], sc, sm, sf};
    __shared__ float tot[13];
    for (int q = 0; q < 13; q++) {
        red[t] = vals[q];
        __syncthreads();
        for (int s = 128; s > 0; s >>= 1) {
            if (t < s) red[t] += red[t + s];
            __syncthreads();
        }
        if (t == 0) tot[q] = red[0];
        __syncthreads();
    }
    if (t == 0) {
        float Ac[5], Bc[5];
        #pragma unroll
        for (int c = 0; c < 5; c++) {
            Ac[c] = -tot[c] / (float)NR;
            Bc[c] = -tot[5 + c] / (float)NR;
        }
        const float ALPHA = 0.55f, BETA = 0.4f;
        const float Lc  = ALPHA * Ac[0] + BETA * Bc[0];
        const float Lm  = ALPHA * Ac[1] + BETA * Bc[1];
        const float Lf  = ALPHA * Ac[2] + BETA * Bc[2];
        const float Lcf = ALPHA * Ac[3] + BETA * Bc[3];
        const float Lmf = ALPHA * Ac[4] + BETA * Bc[4];
        const float scs = tot[10], sms = tot[11], sfs = tot[12];
        const float tot_info = scs + sms + sfs + 1e-8f;
        out[0] = (scs * Lc + sms * Lm + sfs * Lf) / tot_info + 0.2f * (Lcf + Lmf);
    }
}

extern "C" void kernel_launch(void* const* d_in, const int* in_sizes, int n_in,
                              void* d_out, int out_size, void* d_ws, size_t ws_size,
                              hipStream_t stream) {
    const float* z1  = (const float*)d_in[0];
    const float* z2  = (const float*)d_in[1];
    const float* ac  = (const float*)d_in[2];
    const float* am  = (const float*)d_in[3];
    const float* af  = (const float*)d_in[4];
    const float* aca = (const float*)d_in[5];
    const float* ama = (const float*)d_in[6];
    const float* afa = (const float*)d_in[7];

    float* ws   = (float*)d_ws;
    float* rs   = ws;                       // 12*NR
    float* ms   = rs + 12 * NR;             // 20*NR
    float* asum = ms + 20 * NR;             // 6*NR
    float* d12  = asum + 6 * NR;            // NR
    u16* zn1 = (u16*)(d12 + NR);            // NR*DD bf16
    u16* zn2 = zn1 + (size_t)NR * DD;
    int* cnts = (int*)(zn2 + (size_t)NR * DD);   // 6*NR
    int* idx  = cnts + 6 * NR;                    // 6*NR*CAP

    hipMemsetAsync(rs, 0, 12 * NR * sizeof(float), stream);
    norm_kernel<<<NR, 256, 0, stream>>>(z1, z2, zn1, zn2, d12);
    dim3 sg(NR, 6);
    sparsify_kernel<<<sg, 256, 0, stream>>>(ac, am, af, aca, ama, afa, cnts, idx, asum);
    dim3 grid(NR / BN, NR / BM, 2);
    score_kernel<<<grid, 256, 0, stream>>>(zn1, zn2, rs);
    sparse_kernel<<<6 * NR / 4, 256, 0, stream>>>(zn1, zn2, cnts, idx, ms);
    finalize_kernel<<<1, 256, 0, stream>>>(rs, ms, asum, d12, (float*)d_out);
}

// Round 3
// 614.042 us; speedup vs baseline: 1.2529x; 1.2529x over previous
//
#include <hip/hip_runtime.h>
#include <hip/hip_bf16.h>

#define NR 4096
#define DD 512
#define CAP 64   // max nnz per adjacency row (mean 20.5, P(>64) ~ 1e-22)

typedef __bf16 bf16x8 __attribute__((ext_vector_type(8)));
typedef float f32x4 __attribute__((ext_vector_type(4)));
typedef unsigned short u16;

#define AS_GLOBAL(p) ((const __attribute__((address_space(1))) unsigned int*)(p))
#define AS_LDS(p)    ((__attribute__((address_space(3))) unsigned int*)(p))

__device__ __forceinline__ u16 f2bf(float x) {
    __hip_bfloat16 h = __float2bfloat16(x);
    return *reinterpret_cast<u16*>(&h);
}

// ---------------------------------------------------------------------------
// Kernel 1: row-normalize z1,z2 -> bf16, and d12[i] = zn1[i]·zn2[i] (fp32)
// ---------------------------------------------------------------------------
__global__ void norm_kernel(const float* z1, const float* z2,
                            u16* zn1, u16* zn2, float* d12) {
    const int row = blockIdx.x;
    const int t = threadIdx.x;           // 256 threads
    const float* r1 = z1 + (size_t)row * DD;
    const float* r2 = z2 + (size_t)row * DD;
    float a0 = r1[t], a1 = r1[t + 256];
    float b0 = r2[t], b1 = r2[t + 256];
    float ss1 = a0 * a0 + a1 * a1;
    float ss2 = b0 * b0 + b1 * b1;
    #pragma unroll
    for (int m = 1; m < 64; m <<= 1) {
        ss1 += __shfl_xor(ss1, m);
        ss2 += __shfl_xor(ss2, m);
    }
    __shared__ float s1s[4], s2s[4], ds[4];
    const int wid = t >> 6, lane = t & 63;
    if (lane == 0) { s1s[wid] = ss1; s2s[wid] = ss2; }
    __syncthreads();
    const float n1 = s1s[0] + s1s[1] + s1s[2] + s1s[3];
    const float n2 = s2s[0] + s2s[1] + s2s[2] + s2s[3];
    const float inv1 = 1.0f / fmaxf(sqrtf(n1), 1e-12f);
    const float inv2 = 1.0f / fmaxf(sqrtf(n2), 1e-12f);
    const float u0 = a0 * inv1, u1 = a1 * inv1;
    const float v0 = b0 * inv2, v1 = b1 * inv2;
    zn1[(size_t)row * DD + t]       = f2bf(u0);
    zn1[(size_t)row * DD + t + 256] = f2bf(u1);
    zn2[(size_t)row * DD + t]       = f2bf(v0);
    zn2[(size_t)row * DD + t + 256] = f2bf(v1);
    float dp = u0 * v0 + u1 * v1;
    #pragma unroll
    for (int m = 1; m < 64; m <<= 1) dp += __shfl_xor(dp, m);
    if (lane == 0) ds[wid] = dp;
    __syncthreads();
    if (t == 0) d12[row] = ds[0] + ds[1] + ds[2] + ds[3];
}

// ---------------------------------------------------------------------------
// Kernel 2: sparsify the 6 binary adjacency matrices.
// ---------------------------------------------------------------------------
__global__ __launch_bounds__(256)
void sparsify_kernel(const float* m0, const float* m1, const float* m2,
                     const float* m3, const float* m4, const float* m5,
                     int* cnts, int* idx, float* asum) {
    const int row = blockIdx.x;
    const int m = blockIdx.y;
    const int t = threadIdx.x;
    const float* M = (m == 0) ? m0 : (m == 1) ? m1 : (m == 2) ? m2
                   : (m == 3) ? m3 : (m == 4) ? m4 : m5;
    const float* rowp = M + (size_t)row * NR;
    __shared__ int s_cnt;
    __shared__ int s_idx[CAP];
    if (t == 0) s_cnt = 0;
    __syncthreads();
    #pragma unroll
    for (int q = 0; q < 4; q++) {
        const int vi = t + 256 * q;
        const float4 v = ((const float4*)rowp)[vi];
        const int col = vi * 4;
        if (v.x != 0.f) { int p = atomicAdd(&s_cnt, 1); if (p < CAP) s_idx[p] = col; }
        if (v.y != 0.f) { int p = atomicAdd(&s_cnt, 1); if (p < CAP) s_idx[p] = col + 1; }
        if (v.z != 0.f) { int p = atomicAdd(&s_cnt, 1); if (p < CAP) s_idx[p] = col + 2; }
        if (v.w != 0.f) { int p = atomicAdd(&s_cnt, 1); if (p < CAP) s_idx[p] = col + 3; }
    }
    __syncthreads();
    const int c = min(s_cnt, CAP);
    const size_t base = (size_t)m * NR + row;
    if (t < c) idx[base * CAP + t] = s_idx[t];
    if (t == 0) { cnts[base] = c; asum[base] = (float)s_cnt; }
}

// ---------------------------------------------------------------------------
// Kernel 3: tiled Gram + exp row/col sums, exploiting symmetry.
//  mode 0: S11 = zn1·zn1^T, triangle tiles bx>=by  -> pass0 rows+cols
//  mode 1: S12 = zn1·zn2^T, full grid              -> pass1 rows, pass3 cols
//  mode 2: S22 = zn2·zn2^T, triangle tiles         -> pass2 rows+cols
// Partial sums stored to part[((p*3+tau)*32 + slot)*NR + i]; slot algebra
// gives each (p,tau,i) exactly 32 unique writers -> plain stores, no memset.
// Staging: global_load_lds width=16, XOR-swizzled LDS (kb' = kb ^ (row&7)).
// ---------------------------------------------------------------------------
__global__ __launch_bounds__(256, 3)
void score_kernel(const u16* __restrict__ zn1, const u16* __restrict__ zn2,
                  float* __restrict__ part) {
    // --- decode (mode, by, bx) from flat block id ---
    int id = blockIdx.x;
    int mode, by, bx;
    if (id < 1024) {
        mode = 1; by = id >> 5; bx = id & 31;
    } else {
        int k = id - 1024;
        mode = 0;
        if (k >= 528) { k -= 528; mode = 2; }
        int v = (int)((65.0f - sqrtf(4225.0f - 8.0f * (float)k)) * 0.5f);
        if (v < 0) v = 0; if (v > 31) v = 31;
        while (v < 31 && (v + 1) * 32 - ((v + 1) * v) / 2 <= k) v++;
        while (v > 0 && v * 32 - (v * (v - 1)) / 2 > k) v--;
        by = v;
        bx = by + (k - (by * 32 - (by * (by - 1)) / 2));
    }
    const int Ib = by * 128, Jb = bx * 128;
    const u16* Ag = (mode == 2) ? zn2 : zn1;
    const u16* Bg = (mode == 0) ? zn1 : zn2;
    const int p_row = mode;                      // 0,1,2
    const int p_col = (mode == 1) ? 3 : mode;
    const bool do_cols = (mode == 1) || (bx != by);

    __shared__ u16 As[128 * 64];
    __shared__ u16 Bs[128 * 64];
    __shared__ float sRow[2][3][128];
    __shared__ float sCol[2][3][128];

    const int tid = threadIdx.x;
    const int lane = tid & 63;
    const int wid = tid >> 6;
    const int wm = wid >> 1, wn = wid & 1;       // 2x2 waves, 64x64 each
    const int quad = lane >> 4, lcol = lane & 15;

    f32x4 acc[4][4];
    #pragma unroll
    for (int a = 0; a < 4; a++)
        #pragma unroll
        for (int b = 0; b < 4; b++)
            acc[a][b] = (f32x4){0.f, 0.f, 0.f, 0.f};

    // staging chunk geometry: tile = 128 rows x 8 kb-slots(16B). phys slot
    // p = ch*64+lane; r = p>>3; stored kb' = p&7 holds global kb = kb'^(r&7).
    size_t gA[4], gB[4];
    unsigned ldsoff[4];
    #pragma unroll
    for (int cc = 0; cc < 4; cc++) {
        const int ch = cc * 4 + wid;             // wave-uniform chunk id
        const int p = ch * 64 + lane;
        const int r = p >> 3;
        const int kb = (p & 7) ^ (r & 7);
        ldsoff[cc] = (unsigned)ch * 1024u;       // bytes
        gA[cc] = (size_t)(Ib + r) * DD + kb * 8;
        gB[cc] = (size_t)(Jb + r) * DD + kb * 8;
    }

    for (int k0 = 0; k0 < DD; k0 += 64) {
        __syncthreads();                          // frag reads of prev iter done
        #pragma unroll
        for (int cc = 0; cc < 4; cc++) {
            __builtin_amdgcn_global_load_lds(AS_GLOBAL(Ag + gA[cc] + k0),
                                             AS_LDS((char*)As + ldsoff[cc]), 16, 0, 0);
            __builtin_amdgcn_global_load_lds(AS_GLOBAL(Bg + gB[cc] + k0),
                                             AS_LDS((char*)Bs + ldsoff[cc]), 16, 0, 0);
        }
        __syncthreads();                          // drains vmcnt -> data visible
        #pragma unroll
        for (int kk = 0; kk < 64; kk += 32) {
            const int kbb = (kk >> 3) + quad;
            bf16x8 a[4], b[4];
            #pragma unroll
            for (int i = 0; i < 4; i++) {
                const int ra = wm * 64 + i * 16 + lcol;
                const int rb = wn * 64 + i * 16 + lcol;
                a[i] = *(const bf16x8*)&As[ra * 64 + ((kbb ^ (ra & 7)) * 8)];
                b[i] = *(const bf16x8*)&Bs[rb * 64 + ((kbb ^ (rb & 7)) * 8)];
            }
            #pragma unroll
            for (int mi = 0; mi < 4; mi++)
                #pragma unroll
                for (int ni = 0; ni < 4; ni++)
                    acc[mi][ni] = __builtin_amdgcn_mfma_f32_16x16x32_bf16(a[mi], b[ni], acc[mi][ni], 0, 0, 0);
        }
    }

    const float C0 = 1.8033688011112042f;  // log2(e)/0.80
    const float C1 = 2.2542110013890054f;  // log2(e)/0.64
    const float C2 = 2.0037431123457825f;  // log2(e)/0.72

    float colacc[3][4];
    #pragma unroll
    for (int t = 0; t < 3; t++)
        #pragma unroll
        for (int ni = 0; ni < 4; ni++) colacc[t][ni] = 0.f;

    #pragma unroll
    for (int mi = 0; mi < 4; mi++) {
        #pragma unroll
        for (int reg = 0; reg < 4; reg++) {
            float p0 = 0.f, p1 = 0.f, p2 = 0.f;
            #pragma unroll
            for (int ni = 0; ni < 4; ni++) {
                const float s = acc[mi][ni][reg];
                const float e0 = __builtin_amdgcn_exp2f(s * C0);
                const float e1 = __builtin_amdgcn_exp2f(s * C1);
                const float e2 = __builtin_amdgcn_exp2f(s * C2);
                p0 += e0; p1 += e1; p2 += e2;
                colacc[0][ni] += e0; colacc[1][ni] += e1; colacc[2][ni] += e2;
            }
            p0 += __shfl_xor(p0, 1); p0 += __shfl_xor(p0, 2); p0 += __shfl_xor(p0, 4); p0 += __shfl_xor(p0, 8);
            p1 += __shfl_xor(p1, 1); p1 += __shfl_xor(p1, 2); p1 += __shfl_xor(p1, 4); p1 += __shfl_xor(p1, 8);
            p2 += __shfl_xor(p2, 1); p2 += __shfl_xor(p2, 2); p2 += __shfl_xor(p2, 4); p2 += __shfl_xor(p2, 8);
            if (lcol == 0) {
                const int r = wm * 64 + mi * 16 + quad * 4 + reg;
                sRow[wn][0][r] = p0; sRow[wn][1][r] = p1; sRow[wn][2][r] = p2;
            }
        }
    }
    #pragma unroll
    for (int t = 0; t < 3; t++) {
        #pragma unroll
        for (int ni = 0; ni < 4; ni++) {
            float v = colacc[t][ni];
            v += __shfl_xor(v, 16); v += __shfl_xor(v, 32);
            if (quad == 0) sCol[wm][t][wn * 64 + ni * 16 + lcol] = v;
        }
    }
    __syncthreads();
    if (tid < 128) {
        const int i = Ib + tid;
        #pragma unroll
        for (int t = 0; t < 3; t++) {
            const float v = sRow[0][t][tid] + sRow[1][t][tid];
            part[(((size_t)p_row * 3 + t) * 32 + bx) * NR + i] = v;
        }
    } else if (do_cols) {
        const int c = tid - 128;
        const int i = Jb + c;
        #pragma unroll
        for (int t = 0; t < 3; t++) {
            const float v = sCol[0][t][c] + sCol[1][t][c];
            part[(((size_t)p_col * 3 + t) * 32 + by) * NR + i] = v;
        }
    }
}

// ---------------------------------------------------------------------------
// Kernel 4: reduce partials over the 32 slots -> rs[(p*3+tau)*NR + i]
// ---------------------------------------------------------------------------
__global__ __launch_bounds__(256)
void reduce_kernel(const float* __restrict__ part, float* __restrict__ rs) {
    const int g = blockIdx.x * 256 + threadIdx.x;   // 12*4096 threads
    const int pt = g >> 12;
    const int i = g & (NR - 1);
    const float* base = part + ((size_t)pt * 32) * NR + i;
    float s = 0.f;
    #pragma unroll
    for (int k = 0; k < 32; k++) s += base[(size_t)k * NR];
    rs[(size_t)pt * NR + i] = s;
}

// ---------------------------------------------------------------------------
// Kernel 5: sparse masked sums. One wave per (matrix m, row i). No atomics.
// ---------------------------------------------------------------------------
__global__ __launch_bounds__(256)
void sparse_kernel(const u16* zn1, const u16* zn2,
                   const int* cnts, const int* idx, float* ms) {
    const int w = blockIdx.x * 4 + (threadIdx.x >> 6);
    const int lane = threadIdx.x & 63;
    const int m = w >> 12;       // 0..5
    const int i = w & (NR - 1);  // 0..4095

    const float C0 = 1.8033688011112042f;
    const float C1 = 2.2542110013890054f;
    const float C2 = 2.0037431123457825f;

    int nslot; int slot[3]; float coef[3];
    switch (m) {
        case 0: nslot = 2; slot[0] = 0; coef[0] = C0; slot[1] = 3; coef[1] = C1; break;
        case 1: nslot = 2; slot[0] = 1; coef[0] = C0; slot[1] = 4; coef[1] = C2; break;
        case 2: nslot = 1; slot[0] = 2; coef[0] = C0; break;
        case 3: nslot = 1; slot[0] = 0; coef[0] = C0; break;
        case 4: nslot = 1; slot[0] = 1; coef[0] = C0; break;
        default: nslot = 3; slot[0] = 2; coef[0] = C0; slot[1] = 3; coef[1] = C1;
                 slot[2] = 4; coef[2] = C2; break;
    }

    const u16* A = (m < 3) ? zn1 : zn2;
    float a[8];
    {
        const uint4 r = *(const uint4*)(A + (size_t)i * DD + lane * 8);
        const unsigned* u = (const unsigned*)&r;
        #pragma unroll
        for (int q = 0; q < 4; q++) {
            a[2 * q]     = __uint_as_float(u[q] << 16);
            a[2 * q + 1] = __uint_as_float(u[q] & 0xffff0000u);
        }
    }

    const size_t base = (size_t)m * NR + i;
    const int cnt = cnts[base];
    const int* ji = idx + base * CAP;

    float accv[3][2] = {{0.f, 0.f}, {0.f, 0.f}, {0.f, 0.f}};
    for (int q = 0; q < cnt; q++) {
        const int j = ji[q];
        const uint4 r1 = *(const uint4*)(zn1 + (size_t)j * DD + lane * 8);
        const uint4 r2 = *(const uint4*)(zn2 + (size_t)j * DD + lane * 8);
        const unsigned* u1 = (const unsigned*)&r1;
        const unsigned* u2 = (const unsigned*)&r2;
        float d1 = 0.f, d2 = 0.f;
        #pragma unroll
        for (int t = 0; t < 4; t++) {
            d1 += a[2 * t]     * __uint_as_float(u1[t] << 16);
            d1 += a[2 * t + 1] * __uint_as_float(u1[t] & 0xffff0000u);
            d2 += a[2 * t]     * __uint_as_float(u2[t] << 16);
            d2 += a[2 * t + 1] * __uint_as_float(u2[t] & 0xffff0000u);
        }
        #pragma unroll
        for (int msk = 1; msk < 64; msk <<= 1) {
            d1 += __shfl_xor(d1, msk);
            d2 += __shfl_xor(d2, msk);
        }
        const float e1 = (m < 3) ? d1 : d2;   // intra-pass score
        const float e2 = (m < 3) ? d2 : d1;   // inter-pass score
        for (int s = 0; s < nslot; s++) {
            accv[s][0] += __builtin_amdgcn_exp2f(e1 * coef[s]);
            accv[s][1] += __builtin_amdgcn_exp2f(e2 * coef[s]);
        }
    }
    if (lane == 0) {
        const int pb = (m < 3) ? 0 : 2;
        for (int s = 0; s < nslot; s++) {
            ms[((pb)     * 5 + slot[s]) * NR + i] = accv[s][0];
            ms[((pb + 1) * 5 + slot[s]) * NR + i] = accv[s][1];
        }
    }
}

// ---------------------------------------------------------------------------
// Kernel 6: assemble the 10 losses and the final scalar.
// ---------------------------------------------------------------------------
__global__ void finalize_kernel(const float* rs, const float* ms, const float* asum,
                                const float* d12, float* out) {
    const int t = threadIdx.x;   // 256
    const int tA[5] = {0, 0, 0, 1, 2};
    const int kA[5] = {0, 1, 2, 3, 4};
    const int aA[5] = {0, 1, 2, 0, 1};
    const int aB[5] = {3, 4, 5, 5, 5};
    const float it[3] = {1.25f, 1.5625f, 1.3888888888888888f};
    const float e1t[3] = {expf(1.25f), expf(1.5625f), expf(1.3888888888888888f)};

    float LA[5] = {0, 0, 0, 0, 0}, LB[5] = {0, 0, 0, 0, 0};
    float sc = 0.f, sm = 0.f, sf = 0.f;

    for (int i = t; i < NR; i += 256) {
        const float d = d12[i];
        float ed[3];
        ed[0] = __expf(d * it[0]); ed[1] = __expf(d * it[1]); ed[2] = __expf(d * it[2]);
        float R[4][3], M[4][5], A6[6];
        #pragma unroll
        for (int p = 0; p < 4; p++) {
            #pragma unroll
            for (int tt = 0; tt < 3; tt++) R[p][tt] = rs[(p * 3 + tt) * NR + i];
            #pragma unroll
            for (int k = 0; k < 5; k++) M[p][k] = ms[(p * 5 + k) * NR + i];
        }
        #pragma unroll
        for (int a = 0; a < 6; a++) A6[a] = asum[a * NR + i];

        #pragma unroll
        for (int c = 0; c < 5; c++) {
            const int tt = tA[c], k = kA[c];
            float pos = ed[tt] + M[0][k] + M[1][k];
            float den = R[0][tt] + R[1][tt] - e1t[tt];
            float cnt = 2.f * A6[aA[c]] + 1.f;
            LA[c] += __logf(pos / den) / cnt;
            pos = ed[tt] + M[2][k] + M[3][k];
            den = R[2][tt] + R[3][tt] - e1t[tt];
            cnt = 2.f * A6[aB[c]] + 1.f;
            LB[c] += __logf(pos / den) / cnt;
        }
        sc += A6[0]; sm += A6[1]; sf += A6[2];
    }

    __shared__ float red[256];
    float vals[13] = {LA[0], LA[1], LA[2], LA[3], LA[4],
                      LB[0], LB[1], LB[2], LB[3], LB[4], sc, sm, sf};
    __shared__ float tot[13];
    for (int q = 0; q < 13; q++) {
        red[t] = vals[q];
        __syncthreads();
        for (int s = 128; s > 0; s >>= 1) {
            if (t < s) red[t] += red[t + s];
            __syncthreads();
        }
        if (t == 0) tot[q] = red[0];
        __syncthreads();
    }
    if (t == 0) {
        float Ac[5], Bc[5];
        #pragma unroll
        for (int c = 0; c < 5; c++) {
            Ac[c] = -tot[c] / (float)NR;
            Bc[c] = -tot[5 + c] / (float)NR;
        }
        const float ALPHA = 0.55f, BETA = 0.4f;
        const float Lc  = ALPHA * Ac[0] + BETA * Bc[0];
        const float Lm  = ALPHA * Ac[1] + BETA * Bc[1];
        const float Lf  = ALPHA * Ac[2] + BETA * Bc[2];
        const float Lcf = ALPHA * Ac[3] + BETA * Bc[3];
        const float Lmf = ALPHA * Ac[4] + BETA * Bc[4];
        const float scs = tot[10], sms = tot[11], sfs = tot[12];
        const float tot_info = scs + sms + sfs + 1e-8f;
        out[0] = (scs * Lc + sms * Lm + sfs * Lf) / tot_info + 0.2f * (Lcf + Lmf);
    }
}

extern "C" void kernel_launch(void* const* d_in, const int* in_sizes, int n_in,
                              void* d_out, int out_size, void* d_ws, size_t ws_size,
                              hipStream_t stream) {
    const float* z1  = (const float*)d_in[0];
    const float* z2  = (const float*)d_in[1];
    const float* ac  = (const float*)d_in[2];
    const float* am  = (const float*)d_in[3];
    const float* af  = (const float*)d_in[4];
    const float* aca = (const float*)d_in[5];
    const float* ama = (const float*)d_in[6];
    const float* afa = (const float*)d_in[7];

    float* ws   = (float*)d_ws;
    float* rs   = ws;                            // 12*NR
    float* ms   = rs + 12 * NR;                  // 20*NR
    float* asum = ms + 20 * NR;                  // 6*NR
    float* d12  = asum + 6 * NR;                 // NR
    u16* zn1 = (u16*)(d12 + NR);                 // NR*DD bf16
    u16* zn2 = zn1 + (size_t)NR * DD;
    int* cnts = (int*)(zn2 + (size_t)NR * DD);   // 6*NR
    int* idx  = cnts + 6 * NR;                   // 6*NR*CAP
    float* part = (float*)(idx + (size_t)6 * NR * CAP);  // 12*32*NR

    norm_kernel<<<NR, 256, 0, stream>>>(z1, z2, zn1, zn2, d12);
    dim3 sg(NR, 6);
    sparsify_kernel<<<sg, 256, 0, stream>>>(ac, am, af, aca, ama, afa, cnts, idx, asum);
    score_kernel<<<1024 + 2 * 528, 256, 0, stream>>>(zn1, zn2, part);
    sparse_kernel<<<6 * NR / 4, 256, 0, stream>>>(zn1, zn2, cnts, idx, ms);
    reduce_kernel<<<12 * NR / 256, 256, 0, stream>>>(part, rs);
    finalize_kernel<<<1, 256, 0, stream>>>(rs, ms, asum, d12, (float*)d_out);
}

// Round 4
// 585.479 us; speedup vs baseline: 1.3140x; 1.0488x over previous
//
#include <hip/hip_runtime.h>
#include <hip/hip_bf16.h>

#define NR 4096
#define DD 512
#define CAP 64   // max nnz per adjacency row (mean 20.5, P(>64) ~ 1e-22)

typedef __bf16 bf16x8 __attribute__((ext_vector_type(8)));
typedef float f32x4 __attribute__((ext_vector_type(4)));
typedef unsigned short u16;

#define AS_GLOBAL(p) ((const __attribute__((address_space(1))) unsigned int*)(p))
#define AS_LDS(p)    ((__attribute__((address_space(3))) unsigned int*)(p))

__device__ __forceinline__ u16 f2bf(float x) {
    __hip_bfloat16 h = __float2bfloat16(x);
    return *reinterpret_cast<u16*>(&h);
}

__device__ __forceinline__ float blo(unsigned u) { return __uint_as_float(u << 16); }
__device__ __forceinline__ float bhi(unsigned u) { return __uint_as_float(u & 0xffff0000u); }

// ---------------------------------------------------------------------------
// Kernel 1: row-normalize z1,z2 -> bf16, and d12[i] = zn1[i]·zn2[i] (fp32)
// ---------------------------------------------------------------------------
__global__ void norm_kernel(const float* z1, const float* z2,
                            u16* zn1, u16* zn2, float* d12) {
    const int row = blockIdx.x;
    const int t = threadIdx.x;           // 256 threads
    const float* r1 = z1 + (size_t)row * DD;
    const float* r2 = z2 + (size_t)row * DD;
    float a0 = r1[t], a1 = r1[t + 256];
    float b0 = r2[t], b1 = r2[t + 256];
    float ss1 = a0 * a0 + a1 * a1;
    float ss2 = b0 * b0 + b1 * b1;
    #pragma unroll
    for (int m = 1; m < 64; m <<= 1) {
        ss1 += __shfl_xor(ss1, m);
        ss2 += __shfl_xor(ss2, m);
    }
    __shared__ float s1s[4], s2s[4], ds[4];
    const int wid = t >> 6, lane = t & 63;
    if (lane == 0) { s1s[wid] = ss1; s2s[wid] = ss2; }
    __syncthreads();
    const float n1 = s1s[0] + s1s[1] + s1s[2] + s1s[3];
    const float n2 = s2s[0] + s2s[1] + s2s[2] + s2s[3];
    const float inv1 = 1.0f / fmaxf(sqrtf(n1), 1e-12f);
    const float inv2 = 1.0f / fmaxf(sqrtf(n2), 1e-12f);
    const float u0 = a0 * inv1, u1 = a1 * inv1;
    const float v0 = b0 * inv2, v1 = b1 * inv2;
    zn1[(size_t)row * DD + t]       = f2bf(u0);
    zn1[(size_t)row * DD + t + 256] = f2bf(u1);
    zn2[(size_t)row * DD + t]       = f2bf(v0);
    zn2[(size_t)row * DD + t + 256] = f2bf(v1);
    float dp = u0 * v0 + u1 * v1;
    #pragma unroll
    for (int m = 1; m < 64; m <<= 1) dp += __shfl_xor(dp, m);
    if (lane == 0) ds[wid] = dp;
    __syncthreads();
    if (t == 0) d12[row] = ds[0] + ds[1] + ds[2] + ds[3];
}

// ---------------------------------------------------------------------------
// Kernel 2: sparsify the 6 binary adjacency matrices.
// ---------------------------------------------------------------------------
__global__ __launch_bounds__(256)
void sparsify_kernel(const float* m0, const float* m1, const float* m2,
                     const float* m3, const float* m4, const float* m5,
                     int* cnts, int* idx, float* asum) {
    const int row = blockIdx.x;
    const int m = blockIdx.y;
    const int t = threadIdx.x;
    const float* M = (m == 0) ? m0 : (m == 1) ? m1 : (m == 2) ? m2
                   : (m == 3) ? m3 : (m == 4) ? m4 : m5;
    const float* rowp = M + (size_t)row * NR;
    __shared__ int s_cnt;
    __shared__ int s_idx[CAP];
    if (t == 0) s_cnt = 0;
    __syncthreads();
    #pragma unroll
    for (int q = 0; q < 4; q++) {
        const int vi = t + 256 * q;
        const float4 v = ((const float4*)rowp)[vi];
        const int col = vi * 4;
        if (v.x != 0.f) { int p = atomicAdd(&s_cnt, 1); if (p < CAP) s_idx[p] = col; }
        if (v.y != 0.f) { int p = atomicAdd(&s_cnt, 1); if (p < CAP) s_idx[p] = col + 1; }
        if (v.z != 0.f) { int p = atomicAdd(&s_cnt, 1); if (p < CAP) s_idx[p] = col + 2; }
        if (v.w != 0.f) { int p = atomicAdd(&s_cnt, 1); if (p < CAP) s_idx[p] = col + 3; }
    }
    __syncthreads();
    const int c = min(s_cnt, CAP);
    const size_t base = (size_t)m * NR + row;
    if (t < c) idx[base * CAP + t] = s_idx[t];
    if (t == 0) { cnts[base] = c; asum[base] = (float)s_cnt; }
}

// ---------------------------------------------------------------------------
// Kernel 3: tiled Gram + exp row/col sums, exploiting symmetry.
// ---------------------------------------------------------------------------
__global__ __launch_bounds__(256, 3)
void score_kernel(const u16* __restrict__ zn1, const u16* __restrict__ zn2,
                  float* __restrict__ part) {
    int id = blockIdx.x;
    int mode, by, bx;
    if (id < 1024) {
        mode = 1; by = id >> 5; bx = id & 31;
    } else {
        int k = id - 1024;
        mode = 0;
        if (k >= 528) { k -= 528; mode = 2; }
        int v = (int)((65.0f - sqrtf(4225.0f - 8.0f * (float)k)) * 0.5f);
        if (v < 0) v = 0; if (v > 31) v = 31;
        while (v < 31 && (v + 1) * 32 - ((v + 1) * v) / 2 <= k) v++;
        while (v > 0 && v * 32 - (v * (v - 1)) / 2 > k) v--;
        by = v;
        bx = by + (k - (by * 32 - (by * (by - 1)) / 2));
    }
    const int Ib = by * 128, Jb = bx * 128;
    const u16* Ag = (mode == 2) ? zn2 : zn1;
    const u16* Bg = (mode == 0) ? zn1 : zn2;
    const int p_row = mode;
    const int p_col = (mode == 1) ? 3 : mode;
    const bool do_cols = (mode == 1) || (bx != by);

    __shared__ u16 As[128 * 64];
    __shared__ u16 Bs[128 * 64];
    __shared__ float sRow[2][3][128];
    __shared__ float sCol[2][3][128];

    const int tid = threadIdx.x;
    const int lane = tid & 63;
    const int wid = tid >> 6;
    const int wm = wid >> 1, wn = wid & 1;
    const int quad = lane >> 4, lcol = lane & 15;

    f32x4 acc[4][4];
    #pragma unroll
    for (int a = 0; a < 4; a++)
        #pragma unroll
        for (int b = 0; b < 4; b++)
            acc[a][b] = (f32x4){0.f, 0.f, 0.f, 0.f};

    size_t gA[4], gB[4];
    unsigned ldsoff[4];
    #pragma unroll
    for (int cc = 0; cc < 4; cc++) {
        const int ch = cc * 4 + wid;
        const int p = ch * 64 + lane;
        const int r = p >> 3;
        const int kb = (p & 7) ^ (r & 7);
        ldsoff[cc] = (unsigned)ch * 1024u;
        gA[cc] = (size_t)(Ib + r) * DD + kb * 8;
        gB[cc] = (size_t)(Jb + r) * DD + kb * 8;
    }

    for (int k0 = 0; k0 < DD; k0 += 64) {
        __syncthreads();
        #pragma unroll
        for (int cc = 0; cc < 4; cc++) {
            __builtin_amdgcn_global_load_lds(AS_GLOBAL(Ag + gA[cc] + k0),
                                             AS_LDS((char*)As + ldsoff[cc]), 16, 0, 0);
            __builtin_amdgcn_global_load_lds(AS_GLOBAL(Bg + gB[cc] + k0),
                                             AS_LDS((char*)Bs + ldsoff[cc]), 16, 0, 0);
        }
        __syncthreads();
        #pragma unroll
        for (int kk = 0; kk < 64; kk += 32) {
            const int kbb = (kk >> 3) + quad;
            bf16x8 a[4], b[4];
            #pragma unroll
            for (int i = 0; i < 4; i++) {
                const int ra = wm * 64 + i * 16 + lcol;
                const int rb = wn * 64 + i * 16 + lcol;
                a[i] = *(const bf16x8*)&As[ra * 64 + ((kbb ^ (ra & 7)) * 8)];
                b[i] = *(const bf16x8*)&Bs[rb * 64 + ((kbb ^ (rb & 7)) * 8)];
            }
            #pragma unroll
            for (int mi = 0; mi < 4; mi++)
                #pragma unroll
                for (int ni = 0; ni < 4; ni++)
                    acc[mi][ni] = __builtin_amdgcn_mfma_f32_16x16x32_bf16(a[mi], b[ni], acc[mi][ni], 0, 0, 0);
        }
    }

    const float C0 = 1.8033688011112042f;
    const float C1 = 2.2542110013890054f;
    const float C2 = 2.0037431123457825f;

    float colacc[3][4];
    #pragma unroll
    for (int t = 0; t < 3; t++)
        #pragma unroll
        for (int ni = 0; ni < 4; ni++) colacc[t][ni] = 0.f;

    #pragma unroll
    for (int mi = 0; mi < 4; mi++) {
        #pragma unroll
        for (int reg = 0; reg < 4; reg++) {
            float p0 = 0.f, p1 = 0.f, p2 = 0.f;
            #pragma unroll
            for (int ni = 0; ni < 4; ni++) {
                const float s = acc[mi][ni][reg];
                const float e0 = __builtin_amdgcn_exp2f(s * C0);
                const float e1 = __builtin_amdgcn_exp2f(s * C1);
                const float e2 = __builtin_amdgcn_exp2f(s * C2);
                p0 += e0; p1 += e1; p2 += e2;
                colacc[0][ni] += e0; colacc[1][ni] += e1; colacc[2][ni] += e2;
            }
            p0 += __shfl_xor(p0, 1); p0 += __shfl_xor(p0, 2); p0 += __shfl_xor(p0, 4); p0 += __shfl_xor(p0, 8);
            p1 += __shfl_xor(p1, 1); p1 += __shfl_xor(p1, 2); p1 += __shfl_xor(p1, 4); p1 += __shfl_xor(p1, 8);
            p2 += __shfl_xor(p2, 1); p2 += __shfl_xor(p2, 2); p2 += __shfl_xor(p2, 4); p2 += __shfl_xor(p2, 8);
            if (lcol == 0) {
                const int r = wm * 64 + mi * 16 + quad * 4 + reg;
                sRow[wn][0][r] = p0; sRow[wn][1][r] = p1; sRow[wn][2][r] = p2;
            }
        }
    }
    #pragma unroll
    for (int t = 0; t < 3; t++) {
        #pragma unroll
        for (int ni = 0; ni < 4; ni++) {
            float v = colacc[t][ni];
            v += __shfl_xor(v, 16); v += __shfl_xor(v, 32);
            if (quad == 0) sCol[wm][t][wn * 64 + ni * 16 + lcol] = v;
        }
    }
    __syncthreads();
    if (tid < 128) {
        const int i = Ib + tid;
        #pragma unroll
        for (int t = 0; t < 3; t++) {
            const float v = sRow[0][t][tid] + sRow[1][t][tid];
            part[(((size_t)p_row * 3 + t) * 32 + bx) * NR + i] = v;
        }
    } else if (do_cols) {
        const int c = tid - 128;
        const int i = Jb + c;
        #pragma unroll
        for (int t = 0; t < 3; t++) {
            const float v = sCol[0][t][c] + sCol[1][t][c];
            part[(((size_t)p_col * 3 + t) * 32 + by) * NR + i] = v;
        }
    }
}

// ---------------------------------------------------------------------------
// Kernel 4: reduce partials over the 32 slots -> rs[(p*3+tau)*NR + i]
// ---------------------------------------------------------------------------
__global__ __launch_bounds__(256)
void reduce_kernel(const float* __restrict__ part, float* __restrict__ rs) {
    const int g = blockIdx.x * 256 + threadIdx.x;
    const int pt = g >> 12;
    const int i = g & (NR - 1);
    const float* base = part + ((size_t)pt * 32) * NR + i;
    float s = 0.f;
    #pragma unroll
    for (int k = 0; k < 32; k++) s += base[(size_t)k * NR];
    rs[(size_t)pt * NR + i] = s;
}

// ---------------------------------------------------------------------------
// Kernel 5: sparse masked sums, ILP version.
// Wave = one (m,i). 4 groups of 16 lanes; each group owns neighbors
// q = q0+g and q0+4+g -> 8 independent load/dot/butterfly chains in flight.
// Butterfly is 4 stages (16 lanes); ji broadcast from a preloaded register.
// ---------------------------------------------------------------------------
__global__ __launch_bounds__(256)
void sparse_kernel(const u16* __restrict__ zn1, const u16* __restrict__ zn2,
                   const int* __restrict__ cnts, const int* __restrict__ idx,
                   float* __restrict__ ms) {
    const int w = blockIdx.x * 4 + (threadIdx.x >> 6);
    const int lane = threadIdx.x & 63;
    const int g = lane >> 4;          // group 0..3
    const int l = lane & 15;          // lane in group
    const int m = w >> 12;            // 0..5
    const int i = w & (NR - 1);       // 0..4095

    const float C0 = 1.8033688011112042f;
    const float C1 = 2.2542110013890054f;
    const float C2 = 2.0037431123457825f;

    int nslot; int slot[3]; float coef[3];
    switch (m) {
        case 0: nslot = 2; slot[0] = 0; coef[0] = C0; slot[1] = 3; coef[1] = C1; break;
        case 1: nslot = 2; slot[0] = 1; coef[0] = C0; slot[1] = 4; coef[1] = C2; break;
        case 2: nslot = 1; slot[0] = 2; coef[0] = C0; break;
        case 3: nslot = 1; slot[0] = 0; coef[0] = C0; break;
        case 4: nslot = 1; slot[0] = 1; coef[0] = C0; break;
        default: nslot = 3; slot[0] = 2; coef[0] = C0; slot[1] = 3; coef[1] = C1;
                 slot[2] = 4; coef[2] = C2; break;
    }

    // unpack this lane's 32-element slice of a = zn_i (fp32, reused all q)
    const u16* A = (m < 3) ? zn1 : zn2;
    float a[32];
    {
        const uint4* ap = (const uint4*)(A + (size_t)i * DD) + l * 4;
        #pragma unroll
        for (int t = 0; t < 4; t++) {
            const uint4 r = ap[t];
            const unsigned* u = (const unsigned*)&r;
            #pragma unroll
            for (int q = 0; q < 4; q++) {
                a[t * 8 + 2 * q]     = blo(u[q]);
                a[t * 8 + 2 * q + 1] = bhi(u[q]);
            }
        }
    }

    const size_t base = (size_t)m * NR + i;
    const int cnt = cnts[base];
    const int* ji = idx + base * CAP;
    const int jreg = ji[(lane < cnt) ? lane : (cnt > 0 ? cnt - 1 : 0)];

    float acc[3][2] = {{0.f, 0.f}, {0.f, 0.f}, {0.f, 0.f}};

    for (int q0 = 0; q0 < cnt; q0 += 8) {
        const int qa = q0 + g;
        const int qb = qa + 4;
        const bool va = qa < cnt;
        const bool vb = qb < cnt;
        const int ja = __shfl(jreg, va ? qa : 0);
        const int jb = __shfl(jreg, vb ? qb : 0);

        const uint4* p1a = (const uint4*)(zn1 + (size_t)ja * DD) + l * 4;
        const uint4* p2a = (const uint4*)(zn2 + (size_t)ja * DD) + l * 4;
        const uint4* p1b = (const uint4*)(zn1 + (size_t)jb * DD) + l * 4;
        const uint4* p2b = (const uint4*)(zn2 + (size_t)jb * DD) + l * 4;
        uint4 r1a[4], r2a[4], r1b[4], r2b[4];
        #pragma unroll
        for (int t = 0; t < 4; t++) {
            r1a[t] = p1a[t]; r2a[t] = p2a[t];
            r1b[t] = p1b[t]; r2b[t] = p2b[t];
        }

        float s1a0 = 0.f, s1a1 = 0.f, s2a0 = 0.f, s2a1 = 0.f;
        float s1b0 = 0.f, s1b1 = 0.f, s2b0 = 0.f, s2b1 = 0.f;
        #pragma unroll
        for (int t = 0; t < 4; t++) {
            const unsigned* u1a = (const unsigned*)&r1a[t];
            const unsigned* u2a = (const unsigned*)&r2a[t];
            const unsigned* u1b = (const unsigned*)&r1b[t];
            const unsigned* u2b = (const unsigned*)&r2b[t];
            #pragma unroll
            for (int q = 0; q < 4; q++) {
                const float alo = a[t * 8 + 2 * q], ahi = a[t * 8 + 2 * q + 1];
                s1a0 += alo * blo(u1a[q]); s1a1 += ahi * bhi(u1a[q]);
                s2a0 += alo * blo(u2a[q]); s2a1 += ahi * bhi(u2a[q]);
                s1b0 += alo * blo(u1b[q]); s1b1 += ahi * bhi(u1b[q]);
                s2b0 += alo * blo(u2b[q]); s2b1 += ahi * bhi(u2b[q]);
            }
        }
        float d1a = s1a0 + s1a1, d2a = s2a0 + s2a1;
        float d1b = s1b0 + s1b1, d2b = s2b0 + s2b1;

        #pragma unroll
        for (int msk = 1; msk < 16; msk <<= 1) {
            d1a += __shfl_xor(d1a, msk); d2a += __shfl_xor(d2a, msk);
            d1b += __shfl_xor(d1b, msk); d2b += __shfl_xor(d2b, msk);
        }

        const float e1a = (m < 3) ? d1a : d2a, e2a = (m < 3) ? d2a : d1a;
        const float e1b = (m < 3) ? d1b : d2b, e2b = (m < 3) ? d2b : d1b;
        if (va) {
            for (int s = 0; s < nslot; s++) {
                acc[s][0] += __builtin_amdgcn_exp2f(e1a * coef[s]);
                acc[s][1] += __builtin_amdgcn_exp2f(e2a * coef[s]);
            }
        }
        if (vb) {
            for (int s = 0; s < nslot; s++) {
                acc[s][0] += __builtin_amdgcn_exp2f(e1b * coef[s]);
                acc[s][1] += __builtin_amdgcn_exp2f(e2b * coef[s]);
            }
        }
    }

    // combine the 4 groups
    #pragma unroll
    for (int s = 0; s < 3; s++) {
        #pragma unroll
        for (int h = 0; h < 2; h++) {
            float v = acc[s][h];
            v += __shfl_xor(v, 16);
            v += __shfl_xor(v, 32);
            acc[s][h] = v;
        }
    }
    if (lane == 0) {
        const int pb = (m < 3) ? 0 : 2;
        for (int s = 0; s < nslot; s++) {
            ms[((pb)     * 5 + slot[s]) * NR + i] = acc[s][0];
            ms[((pb + 1) * 5 + slot[s]) * NR + i] = acc[s][1];
        }
    }
}

// ---------------------------------------------------------------------------
// Kernel 6: assemble the 10 losses and the final scalar.
// ---------------------------------------------------------------------------
__global__ void finalize_kernel(const float* rs, const float* ms, const float* asum,
                                const float* d12, float* out) {
    const int t = threadIdx.x;   // 256
    const int tA[5] = {0, 0, 0, 1, 2};
    const int kA[5] = {0, 1, 2, 3, 4};
    const int aA[5] = {0, 1, 2, 0, 1};
    const int aB[5] = {3, 4, 5, 5, 5};
    const float it[3] = {1.25f, 1.5625f, 1.3888888888888888f};
    const float e1t[3] = {expf(1.25f), expf(1.5625f), expf(1.3888888888888888f)};

    float LA[5] = {0, 0, 0, 0, 0}, LB[5] = {0, 0, 0, 0, 0};
    float sc = 0.f, sm = 0.f, sf = 0.f;

    for (int i = t; i < NR; i += 256) {
        const float d = d12[i];
        float ed[3];
        ed[0] = __expf(d * it[0]); ed[1] = __expf(d * it[1]); ed[2] = __expf(d * it[2]);
        float R[4][3], M[4][5], A6[6];
        #pragma unroll
        for (int p = 0; p < 4; p++) {
            #pragma unroll
            for (int tt = 0; tt < 3; tt++) R[p][tt] = rs[(p * 3 + tt) * NR + i];
            #pragma unroll
            for (int k = 0; k < 5; k++) M[p][k] = ms[(p * 5 + k) * NR + i];
        }
        #pragma unroll
        for (int a = 0; a < 6; a++) A6[a] = asum[a * NR + i];

        #pragma unroll
        for (int c = 0; c < 5; c++) {
            const int tt = tA[c], k = kA[c];
            float pos = ed[tt] + M[0][k] + M[1][k];
            float den = R[0][tt] + R[1][tt] - e1t[tt];
            float cnt = 2.f * A6[aA[c]] + 1.f;
            LA[c] += __logf(pos / den) / cnt;
            pos = ed[tt] + M[2][k] + M[3][k];
            den = R[2][tt] + R[3][tt] - e1t[tt];
            cnt = 2.f * A6[aB[c]] + 1.f;
            LB[c] += __logf(pos / den) / cnt;
        }
        sc += A6[0]; sm += A6[1]; sf += A6[2];
    }

    __shared__ float red[256];
    float vals[13] = {LA[0], LA[1], LA[2], LA[3], LA[4],
                      LB[0], LB[1], LB[2], LB[3], LB[4], sc, sm, sf};
    __shared__ float tot[13];
    for (int q = 0; q < 13; q++) {
        red[t] = vals[q];
        __syncthreads();
        for (int s = 128; s > 0; s >>= 1) {
            if (t < s) red[t] += red[t + s];
            __syncthreads();
        }
        if (t == 0) tot[q] = red[0];
        __syncthreads();
    }
    if (t == 0) {
        float Ac[5], Bc[5];
        #pragma unroll
        for (int c = 0; c < 5; c++) {
            Ac[c] = -tot[c] / (float)NR;
            Bc[c] = -tot[5 + c] / (float)NR;
        }
        const float ALPHA = 0.55f, BETA = 0.4f;
        const float Lc  = ALPHA * Ac[0] + BETA * Bc[0];
        const float Lm  = ALPHA * Ac[1] + BETA * Bc[1];
        const float Lf  = ALPHA * Ac[2] + BETA * Bc[2];
        const float Lcf = ALPHA * Ac[3] + BETA * Bc[3];
        const float Lmf = ALPHA * Ac[4] + BETA * Bc[4];
        const float scs = tot[10], sms = tot[11], sfs = tot[12];
        const float tot_info = scs + sms + sfs + 1e-8f;
        out[0] = (scs * Lc + sms * Lm + sfs * Lf) / tot_info + 0.2f * (Lcf + Lmf);
    }
}

extern "C" void kernel_launch(void* const* d_in, const int* in_sizes, int n_in,
                              void* d_out, int out_size, void* d_ws, size_t ws_size,
                              hipStream_t stream) {
    const float* z1  = (const float*)d_in[0];
    const float* z2  = (const float*)d_in[1];
    const float* ac  = (const float*)d_in[2];
    const float* am  = (const float*)d_in[3];
    const float* af  = (const float*)d_in[4];
    const float* aca = (const float*)d_in[5];
    const float* ama = (const float*)d_in[6];
    const float* afa = (const float*)d_in[7];

    float* ws   = (float*)d_ws;
    float* rs   = ws;                            // 12*NR
    float* ms   = rs + 12 * NR;                  // 20*NR
    float* asum = ms + 20 * NR;                  // 6*NR
    float* d12  = asum + 6 * NR;                 // NR
    u16* zn1 = (u16*)(d12 + NR);                 // NR*DD bf16
    u16* zn2 = zn1 + (size_t)NR * DD;
    int* cnts = (int*)(zn2 + (size_t)NR * DD);   // 6*NR
    int* idx  = cnts + 6 * NR;                   // 6*NR*CAP
    float* part = (float*)(idx + (size_t)6 * NR * CAP);  // 12*32*NR

    norm_kernel<<<NR, 256, 0, stream>>>(z1, z2, zn1, zn2, d12);
    dim3 sg(NR, 6);
    sparsify_kernel<<<sg, 256, 0, stream>>>(ac, am, af, aca, ama, afa, cnts, idx, asum);
    score_kernel<<<1024 + 2 * 528, 256, 0, stream>>>(zn1, zn2, part);
    sparse_kernel<<<6 * NR / 4, 256, 0, stream>>>(zn1, zn2, cnts, idx, ms);
    reduce_kernel<<<12 * NR / 256, 256, 0, stream>>>(part, rs);
    finalize_kernel<<<1, 256, 0, stream>>>(rs, ms, asum, d12, (float*)d_out);
}